// Round 3
// baseline (1040.245 us; speedup 1.0000x reference)
//
#include <hip/hip_runtime.h>
#include <hip/hip_bf16.h>

// i_in[post[s]] += weights[s] * (inputs_t[0][pre[s]] > 0)
// N_SYN=30M, N_POST=200k, N_SOURCE=17400.
//
// Round-1 evidence: device-scope atomicAdd writes ~32B/op past L2
// (WRITE_SIZE 469 MB for an 800 KB output) -> atomic-path BW bound at
// ~630 GB/s. Fix: per-XCD output replicas in d_ws + WORKGROUP-scope
// atomics that execute in the local (per-XCD) TCC, where the 800 KB
// replica stays cache-resident. XCD identified at runtime via
// s_getreg(HW_REG_XCC_ID) (HW-verified on MI355X). Dense reduce of the
// 8 replicas afterwards. Nontemporal loads keep the 360 MB use-once
// stream from evicting replica lines out of the 4 MB per-XCD L2.
//
// NOTE: __builtin_nontemporal_load requires native clang vector types,
// not HIP_vector_type structs -> use ext_vector_type typedefs.

#define NREP 8

typedef int   vint4   __attribute__((ext_vector_type(4)));
typedef float vfloat4 __attribute__((ext_vector_type(4)));

__global__ __launch_bounds__(256) void syn_scatter_xcd(
    const int* __restrict__ act,          // inputs_t[0], N_SOURCE ints (0/1)
    const vint4* __restrict__ idx4,       // indices as int4: 2 synapses per vec
    const vfloat4* __restrict__ w4,       // weights as float4: 4 synapses
    float* __restrict__ rep,              // NREP * n_post floats, pre-zeroed
    int n_vec, int n_post)
{
    // Which XCD am I physically on? (workgroup never migrates)
    int xcc;
    asm volatile("s_getreg_b32 %0, hwreg(HW_REG_XCC_ID)" : "=s"(xcc));
    float* out = rep + (size_t)(xcc & (NREP - 1)) * (size_t)n_post;

    int t = blockIdx.x * blockDim.x + threadIdx.x;
    if (t >= n_vec) return;

    vint4   ia = __builtin_nontemporal_load(&idx4[2 * t]);
    vint4   ib = __builtin_nontemporal_load(&idx4[2 * t + 1]);
    vfloat4 wv = __builtin_nontemporal_load(&w4[t]);

    // Workgroup-scope atomics: plain global_atomic_add_f32, executed in the
    // local XCD's TCC; replica lines stay dirty in L2 (no per-op HBM RMW).
    if (act[ia.y] > 0)
        __hip_atomic_fetch_add(&out[ia.x], wv.x, __ATOMIC_RELAXED, __HIP_MEMORY_SCOPE_WORKGROUP);
    if (act[ia.w] > 0)
        __hip_atomic_fetch_add(&out[ia.z], wv.y, __ATOMIC_RELAXED, __HIP_MEMORY_SCOPE_WORKGROUP);
    if (act[ib.y] > 0)
        __hip_atomic_fetch_add(&out[ib.x], wv.z, __ATOMIC_RELAXED, __HIP_MEMORY_SCOPE_WORKGROUP);
    if (act[ib.w] > 0)
        __hip_atomic_fetch_add(&out[ib.z], wv.w, __ATOMIC_RELAXED, __HIP_MEMORY_SCOPE_WORKGROUP);
}

__global__ __launch_bounds__(256) void reduce_reps(
    const float* __restrict__ rep, float* __restrict__ out, int n_post)
{
    int i = blockIdx.x * blockDim.x + threadIdx.x;
    if (i < n_post) {
        float s = 0.f;
        #pragma unroll
        for (int r = 0; r < NREP; ++r)
            s += rep[(size_t)r * n_post + i];
        out[i] = s;
    }
}

// Fallback (ws too small): round-1 direct device-scope atomic kernel.
__global__ __launch_bounds__(256) void syn_scatter_direct(
    const int* __restrict__ act, const vint4* __restrict__ idx4,
    const vfloat4* __restrict__ w4, float* __restrict__ out, int n_vec)
{
    int t = blockIdx.x * blockDim.x + threadIdx.x;
    if (t >= n_vec) return;
    vint4 ia = idx4[2 * t], ib = idx4[2 * t + 1];
    vfloat4 wv = w4[t];
    if (act[ia.y] > 0) atomicAdd(&out[ia.x], wv.x);
    if (act[ia.w] > 0) atomicAdd(&out[ia.z], wv.y);
    if (act[ib.y] > 0) atomicAdd(&out[ib.x], wv.z);
    if (act[ib.w] > 0) atomicAdd(&out[ib.z], wv.w);
}

extern "C" void kernel_launch(void* const* d_in, const int* in_sizes, int n_in,
                              void* d_out, int out_size, void* d_ws, size_t ws_size,
                              hipStream_t stream) {
    const int*   inputs_t = (const int*)d_in[0];   // (1, 17400) int32
    const int*   indices  = (const int*)d_in[1];   // (30M, 2) int32
    const float* weights  = (const float*)d_in[2]; // (30M,) float32

    const int n_syn  = in_sizes[2];
    const int n_post = out_size;
    const int n_vec  = n_syn / 4;                  // 30M divisible by 4

    const size_t rep_bytes = (size_t)NREP * (size_t)n_post * sizeof(float);
    const int block = 256;

    if (ws_size >= rep_bytes) {
        float* rep = (float*)d_ws;
        (void)hipMemsetAsync(rep, 0, rep_bytes, stream);

        const int grid = (n_vec + block - 1) / block;
        syn_scatter_xcd<<<grid, block, 0, stream>>>(
            inputs_t, (const vint4*)indices, (const vfloat4*)weights,
            rep, n_vec, n_post);

        const int rgrid = (n_post + block - 1) / block;
        reduce_reps<<<rgrid, block, 0, stream>>>(rep, (float*)d_out, n_post);
    } else {
        (void)hipMemsetAsync(d_out, 0, (size_t)n_post * sizeof(float), stream);
        const int grid = (n_vec + block - 1) / block;
        syn_scatter_direct<<<grid, block, 0, stream>>>(
            inputs_t, (const vint4*)indices, (const vfloat4*)weights,
            (float*)d_out, n_vec);
    }
}

// Round 4
// 653.095 us; speedup vs baseline: 1.5928x; 1.5928x over previous
//
#include <hip/hip_runtime.h>

// i_in[post[s]] += w[s] * (act[pre[s]] > 0);  N_SYN=30M, N_POST=200k, N_SRC=17400.
//
// Round-1/3 evidence: non-returning fp32 global atomics cost ~32B HBM-side RMW
// each (WRITE_SIZE = 15M x 32B regardless of scope) -> ~20.6 G atomic/s wall,
// 727 us. Fix: eliminate fp32 global atomics entirely.
//   Phase 1: stream indices+weights once, drop inactive synapses, partition
//            active (local_post, w) pairs into NB=512 post-range buckets in
//            d_ws. Per-block LDS staging; one uint cursor reservation per
//            (block,bucket) on padded cursor lines (~1.4M int atomics total).
//   Phase 2: one block per bucket; LDS float-atomic histogram (391 bins),
//            dense coalesced write of the output slice. No memset of d_out
//            needed (every post written exactly once).
// Sections if ws_size is too small for one pass; direct-atomic fallback if
// ws_size is tiny.

typedef int   vint4   __attribute__((ext_vector_type(4)));
typedef float vfloat4 __attribute__((ext_vector_type(4)));

#define NB          512
#define P1_BLK      256
#define ITER        11
#define CHUNK       (ITER * P1_BLK * 4)   // 11264 synapses per phase-1 block
#define ECAP        7040                  // LDS pair-staging capacity (62.5% of CHUNK; ~24 sigma)
#define CUR_STRIDE  32                    // one cursor per 128B line (spread TCC atomic traffic)

__global__ __launch_bounds__(P1_BLK) void p1_partition(
    const int* __restrict__ act,
    const vint4* __restrict__ idx4,
    const vfloat4* __restrict__ w4,
    unsigned* __restrict__ cursors,            // NB * CUR_STRIDE uints, pre-zeroed
    unsigned long long* __restrict__ pairs,    // NB regions of `cap` 8B entries
    int sec_base_vec, int sec_nvec, int cap, int bw)
{
    __shared__ unsigned           lds_cnt[NB];
    __shared__ unsigned           lds_base[NB];
    __shared__ unsigned           lds_npairs;
    __shared__ unsigned long long lds_ent[ECAP];  // hi32 = w bits, lo32 = local|b<<9|r<<18

    const int tid  = threadIdx.x;
    const int lane = tid & 63;
    for (int i = tid; i < NB; i += P1_BLK) lds_cnt[i] = 0;
    if (tid == 0) lds_npairs = 0;
    __syncthreads();

    const int vbase = sec_base_vec + blockIdx.x * (ITER * P1_BLK);

    for (int it = 0; it < ITER; ++it) {
        int  v   = vbase + it * P1_BLK + tid;
        bool inb = (v - sec_base_vec) < sec_nvec;
        vint4   ia = {0,0,0,0}, ib = {0,0,0,0};
        vfloat4 wv = {0.f,0.f,0.f,0.f};
        if (inb) {
            ia = __builtin_nontemporal_load(&idx4[2 * v]);
            ib = __builtin_nontemporal_load(&idx4[2 * v + 1]);
            wv = __builtin_nontemporal_load(&w4[v]);
        }
        const int   posts[4] = {ia.x, ia.z, ib.x, ib.z};
        const int   pres[4]  = {ia.y, ia.w, ib.y, ib.w};
        const float wsv[4]   = {wv.x, wv.y, wv.z, wv.w};

        #pragma unroll
        for (int j = 0; j < 4; ++j) {
            bool actv = inb && (act[pres[j]] > 0);
            // wave-aggregated slot allocation (1 LDS atomic per wave per j)
            unsigned long long mask = __ballot(actv);
            unsigned prefix = (unsigned)__popcll(mask & ((1ull << lane) - 1ull));
            unsigned slotbase = 0;
            if (actv && prefix == 0)
                slotbase = atomicAdd(&lds_npairs, (unsigned)__popcll(mask));
            int src = (mask == 0ull) ? 0 : (__ffsll((long long)mask) - 1);
            slotbase = __shfl(slotbase, src);
            if (actv) {
                unsigned slot = slotbase + prefix;
                if (slot < ECAP) {
                    unsigned post  = (unsigned)posts[j];
                    unsigned b     = post / (unsigned)bw;
                    unsigned local = post - b * (unsigned)bw;       // < bw <= 512 (9 bits)
                    unsigned r     = atomicAdd(&lds_cnt[b], 1u);    // < CHUNK (14 bits)
                    unsigned packed = local | (b << 9) | (r << 18);
                    lds_ent[slot] =
                        ((unsigned long long)__float_as_uint(wsv[j]) << 32) | packed;
                }
            }
        }
    }
    __syncthreads();

    // one global reservation per (block, bucket); cursors padded to own lines
    for (int b = tid; b < NB; b += P1_BLK)
        lds_base[b] = atomicAdd(&cursors[b * CUR_STRIDE], lds_cnt[b]);
    __syncthreads();

    unsigned np = lds_npairs; if (np > ECAP) np = ECAP;
    for (unsigned s = tid; s < np; s += P1_BLK) {
        unsigned long long e = lds_ent[s];
        unsigned packed = (unsigned)e;
        unsigned local  = packed & 511u;
        unsigned b      = (packed >> 9) & 511u;
        unsigned r      = packed >> 18;
        unsigned dst    = lds_base[b] + r;
        if (dst < (unsigned)cap)
            pairs[(size_t)b * (size_t)cap + dst] =
                (e & 0xffffffff00000000ull) | (unsigned long long)local;
    }
}

__global__ __launch_bounds__(1024) void p2_accum(
    const unsigned long long* __restrict__ pairs,
    const unsigned* __restrict__ cursors,
    float* __restrict__ out,
    int cap, int bw, int n_post, int first)
{
    __shared__ float hist[512];               // bw <= 512
    const int b   = blockIdx.x;
    const int tid = threadIdx.x;
    for (int i = tid; i < bw; i += 1024) hist[i] = 0.f;
    __syncthreads();

    unsigned n = cursors[b * CUR_STRIDE];
    if (n > (unsigned)cap) n = (unsigned)cap;
    const unsigned long long* p = pairs + (size_t)b * (size_t)cap;
    for (unsigned i = tid; i < n; i += 1024) {
        unsigned long long e = p[i];
        unsigned local = (unsigned)e & 511u;
        float    w     = __uint_as_float((unsigned)(e >> 32));
        atomicAdd(&hist[local], w);           // ds_add_f32 — LDS-rate, no HBM RMW
    }
    __syncthreads();

    for (int l = tid; l < bw; l += 1024) {
        int g = b * bw + l;
        if (g < n_post) {
            float v = hist[l];
            out[g] = first ? v : (out[g] + v);
        }
    }
}

// Fallback: known-good direct device-atomic kernel (727 us).
__global__ __launch_bounds__(256) void syn_scatter_direct(
    const int* __restrict__ act, const vint4* __restrict__ idx4,
    const vfloat4* __restrict__ w4, float* __restrict__ out, int n_vec)
{
    int t = blockIdx.x * blockDim.x + threadIdx.x;
    if (t >= n_vec) return;
    vint4 ia = idx4[2 * t], ib = idx4[2 * t + 1];
    vfloat4 wv = w4[t];
    if (act[ia.y] > 0) atomicAdd(&out[ia.x], wv.x);
    if (act[ia.w] > 0) atomicAdd(&out[ia.z], wv.y);
    if (act[ib.y] > 0) atomicAdd(&out[ib.x], wv.z);
    if (act[ib.w] > 0) atomicAdd(&out[ib.z], wv.w);
}

extern "C" void kernel_launch(void* const* d_in, const int* in_sizes, int n_in,
                              void* d_out, int out_size, void* d_ws, size_t ws_size,
                              hipStream_t stream) {
    const int*   act     = (const int*)d_in[0];    // (1, 17400) int32
    const int*   indices = (const int*)d_in[1];    // (30M, 2) int32
    const float* weights = (const float*)d_in[2];  // (30M,) float32

    const int n_syn  = in_sizes[2];
    const int n_post = out_size;
    const int n_vec  = n_syn / 4;
    const int bw     = (n_post + NB - 1) / NB;     // 391 for n_post=200000

    const size_t cur_bytes = (size_t)NB * CUR_STRIDE * sizeof(unsigned);
    const size_t avail     = ws_size > cur_bytes ? ws_size - cur_bytes : 0;
    const long long cap_avail   = (long long)(avail / ((size_t)NB * 8ull));
    const long long sec_max_syn = cap_avail * NB * 4ll / 3ll;   // cap covers 75% of section

    bool ok = (bw <= 512) && (n_syn % 4 == 0) && (cap_avail >= 1024) && (sec_max_syn > 0);
    int  nsec = ok ? (int)((n_syn + sec_max_syn - 1) / sec_max_syn) : 1000;

    if (!ok || nsec > 8) {
        (void)hipMemsetAsync(d_out, 0, (size_t)n_post * sizeof(float), stream);
        const int grid = (n_vec + 255) / 256;
        syn_scatter_direct<<<grid, 256, 0, stream>>>(
            act, (const vint4*)indices, (const vfloat4*)weights, (float*)d_out, n_vec);
        return;
    }

    unsigned*           cursors = (unsigned*)d_ws;
    unsigned long long* pairs   = (unsigned long long*)((char*)d_ws + cur_bytes);

    const int vec_per_sec = (n_vec + nsec - 1) / nsec;
    long long cap_ll = ((long long)vec_per_sec * 4ll * 3ll) / (4ll * NB) + 64;
    if (cap_ll > cap_avail) cap_ll = cap_avail;
    const int cap = (int)cap_ll;

    for (int s = 0; s < nsec; ++s) {
        int v0 = s * vec_per_sec;
        int nv = n_vec - v0; if (nv > vec_per_sec) nv = vec_per_sec;
        if (nv <= 0) break;
        (void)hipMemsetAsync(cursors, 0, cur_bytes, stream);
        int blocks = (nv * 4 + CHUNK - 1) / CHUNK;
        p1_partition<<<blocks, P1_BLK, 0, stream>>>(
            act, (const vint4*)indices, (const vfloat4*)weights,
            cursors, pairs, v0, nv, cap, bw);
        p2_accum<<<NB, 1024, 0, stream>>>(
            pairs, cursors, (float*)d_out, cap, bw, n_post, s == 0 ? 1 : 0);
    }
}

// Round 5
// 516.984 us; speedup vs baseline: 2.0121x; 1.2633x over previous
//
#include <hip/hip_runtime.h>

// i_in[post[s]] += w[s] * (act[pre[s]] > 0);  N_SYN=30M, N_POST=200k, N_SRC=17400.
//
// Evidence so far: fp32 global atomics cost ~32B HBM RMW each (wall ~660 GB/s,
// 727 us). Round-4 two-phase bucket sort: 653 us, p1 = 87% of time, limited by
// (a) uncoalesced per-pair scatter (WRITE 220MB vs 60 logical), (b) random
// global act[] gather (~1 addr/cyc TA throughput), (c) 20% occupancy.
//
// This version:
//   p0: pack act into a 2.2 KB bitmask (global gather -> LDS bit test in p1).
//   p1: per-block bucket-ordered LDS image: NB=391 buckets x MINICAP=30 slots
//       x 4B packed (w with low 9 mantissa bits = post&511). Insert = 1 LDS
//       atomicAdd; overflow (rare, ~1e3 total) -> direct device atomicAdd on
//       out (correct for any distribution). Whole padded region streamed to
//       global with dwordx4 -> fully coalesced, ZERO global atomics hot path.
//   p2: one block per bucket: gather its segments, LDS fp32 histogram,
//       out[g] += hist (out pre-zeroed; overflow atomics already landed).
// Sections if ws too small for one pass; direct-atomic fallback if tiny.

typedef int   vint4   __attribute__((ext_vector_type(4)));
typedef float vfloat4 __attribute__((ext_vector_type(4)));
typedef unsigned int uint;

#define P1_BLK    256
#define P1_ITER   12
#define CHUNK     (P1_BLK * P1_ITER * 4)     // 12288 synapses per p1 block
#define MINICAP   30                          // slots per (block,bucket); mean ~15.7
#define NB_MAX    392                         // buckets of 512 posts: ceil(200192/512)
#define STRIDE_MAX 11744                      // (391*30+31)&~31 dwords per block region
#define NW_MAX    544                         // act bitmask words: ceil(17400/32)
#define P2_BLK    1024
#define NBLK_MAX  2448                        // ceil(30M/12288)=2442

__global__ __launch_bounds__(256) void p0_bitmask(
    const int* __restrict__ act, uint* __restrict__ bits_g, int n_src)
{
    int w  = blockIdx.x * blockDim.x + threadIdx.x;
    int nw = (n_src + 31) >> 5;
    if (w < nw) {
        uint m = 0;
        int base = w << 5;
        #pragma unroll
        for (int j = 0; j < 32; ++j) {
            int s = base + j;
            if (s < n_src && act[s] > 0) m |= (1u << j);
        }
        bits_g[w] = m;
    }
}

__global__ __launch_bounds__(P1_BLK) void p1_bucketize(
    const uint* __restrict__ bits_g,
    const vint4* __restrict__ idx4,
    const vfloat4* __restrict__ w4,
    uint* __restrict__ cnt_g,          // [nb][blocks_s] counts
    uint* __restrict__ pairs_g,        // [blocks_s][stride_dw] packed pairs
    float* __restrict__ out,           // overflow target (pre-zeroed)
    int sec_base_vec, int sec_nvec, int blocks_s, int nb, int nwords, int stride_dw)
{
    __shared__ uint bits[NW_MAX];
    __shared__ uint cnt[NB_MAX];
    __shared__ __align__(16) uint ord[STRIDE_MAX];

    const int tid = threadIdx.x;
    for (int i = tid; i < nwords; i += P1_BLK) bits[i] = bits_g[i];
    for (int i = tid; i < nb;     i += P1_BLK) cnt[i] = 0;
    __syncthreads();

    const int vbase = sec_base_vec + blockIdx.x * (P1_ITER * P1_BLK);

    for (int it = 0; it < P1_ITER; ++it) {
        int v = vbase + it * P1_BLK + tid;
        if ((v - sec_base_vec) < sec_nvec) {
            vint4   ia = __builtin_nontemporal_load(&idx4[2 * v]);
            vint4   ib = __builtin_nontemporal_load(&idx4[2 * v + 1]);
            vfloat4 wv = __builtin_nontemporal_load(&w4[v]);

            const int   posts[4] = {ia.x, ia.z, ib.x, ib.z};
            const int   pres[4]  = {ia.y, ia.w, ib.y, ib.w};
            const float wsv[4]   = {wv.x, wv.y, wv.z, wv.w};

            #pragma unroll
            for (int j = 0; j < 4; ++j) {
                uint pre = (uint)pres[j];
                if ((bits[pre >> 5] >> (pre & 31u)) & 1u) {
                    uint post = (uint)posts[j];
                    uint b    = post >> 9;
                    uint r    = atomicAdd(&cnt[b], 1u);
                    if (r < MINICAP) {
                        uint pk = (__float_as_uint(wsv[j]) & 0xFFFFFE00u) | (post & 511u);
                        ord[b * MINICAP + r] = pk;
                    } else {
                        atomicAdd(&out[post], wsv[j]);   // rare overflow
                    }
                }
            }
        }
    }
    __syncthreads();

    // counts out (strided scatter, 391 dwords/block — small)
    for (int b = tid; b < nb; b += P1_BLK) {
        uint c = cnt[b];
        cnt_g[(size_t)b * (size_t)blocks_s + blockIdx.x] = (c > MINICAP) ? MINICAP : c;
    }
    // padded region out: fully coalesced dwordx4 stream (garbage slots ok)
    vint4* dst = (vint4*)(pairs_g + (size_t)blockIdx.x * (size_t)stride_dw);
    const vint4* src = (const vint4*)ord;
    for (int i = tid; i < (stride_dw >> 2); i += P1_BLK)
        dst[i] = src[i];
}

__global__ __launch_bounds__(P2_BLK) void p2_accum(
    const uint* __restrict__ pairs_g,
    const uint* __restrict__ cnt_g,
    float* __restrict__ out,
    int blocks_s, int nb, int stride_dw, int n_post)
{
    __shared__ float hist[512];
    __shared__ unsigned short cntl[NBLK_MAX];

    const int b   = blockIdx.x;
    const int tid = threadIdx.x;
    for (int i = tid; i < 512; i += P2_BLK) hist[i] = 0.f;
    for (int i = tid; i < blocks_s; i += P2_BLK)
        cntl[i] = (unsigned short)cnt_g[(size_t)b * (size_t)blocks_s + i];
    __syncthreads();

    const int total = blocks_s * MINICAP;
    const size_t bucket_off = (size_t)b * MINICAP;
    for (int i = tid; i < total; i += P2_BLK) {
        int blk  = i / MINICAP;              // const div -> magic mul
        int slot = i - blk * MINICAP;
        if (slot < (int)cntl[blk]) {
            uint pk = pairs_g[(size_t)blk * (size_t)stride_dw + bucket_off + slot];
            atomicAdd(&hist[pk & 511u], __uint_as_float(pk & 0xFFFFFE00u));
        }
    }
    __syncthreads();

    for (int l = tid; l < 512; l += P2_BLK) {
        int g = (b << 9) + l;
        if (g < n_post) out[g] += hist[l];   // disjoint per block; overflow already in out
    }
}

// Fallback: known-good direct device-atomic kernel (727 us).
__global__ __launch_bounds__(256) void syn_scatter_direct(
    const int* __restrict__ act, const vint4* __restrict__ idx4,
    const vfloat4* __restrict__ w4, float* __restrict__ out, int n_vec)
{
    int t = blockIdx.x * blockDim.x + threadIdx.x;
    if (t >= n_vec) return;
    vint4 ia = idx4[2 * t], ib = idx4[2 * t + 1];
    vfloat4 wv = w4[t];
    if (act[ia.y] > 0) atomicAdd(&out[ia.x], wv.x);
    if (act[ia.w] > 0) atomicAdd(&out[ia.z], wv.y);
    if (act[ib.y] > 0) atomicAdd(&out[ib.x], wv.z);
    if (act[ib.w] > 0) atomicAdd(&out[ib.z], wv.w);
}

extern "C" void kernel_launch(void* const* d_in, const int* in_sizes, int n_in,
                              void* d_out, int out_size, void* d_ws, size_t ws_size,
                              hipStream_t stream) {
    const int*   act     = (const int*)d_in[0];    // (1, n_src) int32
    const int*   indices = (const int*)d_in[1];    // (n_syn, 2) int32
    const float* weights = (const float*)d_in[2];  // (n_syn,) float32

    const int n_src  = in_sizes[0];
    const int n_syn  = in_sizes[2];
    const int n_post = out_size;
    const int n_vec  = n_syn / 4;

    const int nb        = (n_post + 511) >> 9;
    const int nwords    = (n_src + 31) >> 5;
    const int stride_dw = (nb * MINICAP + 31) & ~31;
    const int nblk_tot  = (n_syn + CHUNK - 1) / CHUNK;

    const size_t per_blk_bytes = (size_t)nb * 4 + (size_t)stride_dw * 4;
    const size_t head_bytes    = 4096;  // bitmask region
    long long nblk_fit = (ws_size > head_bytes)
                       ? (long long)((ws_size - head_bytes) / per_blk_bytes) : 0;

    bool ok = (n_syn % 4 == 0) && (nb <= NB_MAX - 1) && (nwords <= NW_MAX) &&
              (stride_dw <= STRIDE_MAX) && (nblk_tot <= NBLK_MAX) && (nblk_fit >= 1);
    int nsec = ok ? (int)((nblk_tot + nblk_fit - 1) / nblk_fit) : 1000;

    if (!ok || nsec > 8) {
        (void)hipMemsetAsync(d_out, 0, (size_t)n_post * sizeof(float), stream);
        const int grid = (n_vec + 255) / 256;
        syn_scatter_direct<<<grid, 256, 0, stream>>>(
            act, (const vint4*)indices, (const vfloat4*)weights, (float*)d_out, n_vec);
        return;
    }

    const int nblk_s = (nblk_tot + nsec - 1) / nsec;       // blocks in largest section
    uint* bits_g = (uint*)d_ws;
    uint* cnt_g  = (uint*)((char*)d_ws + head_bytes);
    size_t cnt_bytes = ((size_t)nb * (size_t)nblk_s * 4 + 255) & ~(size_t)255;
    uint* pairs_g = (uint*)((char*)cnt_g + cnt_bytes);

    (void)hipMemsetAsync(d_out, 0, (size_t)n_post * sizeof(float), stream);
    p0_bitmask<<<(nwords + 255) / 256, 256, 0, stream>>>(act, bits_g, n_src);

    const int vec_per_sec = nblk_s * (CHUNK / 4);
    for (int s = 0; s < nsec; ++s) {
        int v0 = s * vec_per_sec;
        int nv = n_vec - v0; if (nv > vec_per_sec) nv = vec_per_sec;
        if (nv <= 0) break;
        int blocks_s = (nv * 4 + CHUNK - 1) / CHUNK;
        p1_bucketize<<<blocks_s, P1_BLK, 0, stream>>>(
            bits_g, (const vint4*)indices, (const vfloat4*)weights,
            cnt_g, pairs_g, (float*)d_out,
            v0, nv, blocks_s, nb, nwords, stride_dw);
        p2_accum<<<nb, P2_BLK, 0, stream>>>(
            pairs_g, cnt_g, (float*)d_out, blocks_s, nb, stride_dw, n_post);
    }
}